// Round 7
// baseline (650.000 us; speedup 1.0000x reference)
//
#include <hip/hip_runtime.h>
#include <hip/hip_bf16.h>
#include <cstdint>
#include <cstddef>

#define DIM  128
#define NREL 8
#define SCB  4096   // elements per scan block (16 per thread)
#define CPB  16     // cols per fused block (32 KB LDS, 512-thr blocks -> 4 blocks/CU = 32 waves)

typedef __attribute__((ext_vector_type(8))) short short8;
typedef __attribute__((ext_vector_type(4))) float f32x4;

static inline int cdiv(int a, int b){ return (a + b - 1) / b; }

// single-instruction packed fp32x2 -> bf16x2 (RNE)
__device__ inline uint32_t packrn(float lo, float hi){
    __hip_bfloat162 h = __float22bfloat162_rn(make_float2(lo, hi));
    union { __hip_bfloat162 h; uint32_t u; } v; v.h = h; return v.u;
}
__device__ inline float bf2f(uint32_t lo16){
    union { uint32_t u; float f; } v; v.u = lo16 << 16; return v.f;
}
__device__ inline float asf(int u){
    union { int i; float f; } v; v.i = u; return v.f;
}

// ---- fused prep: [0,nb4) xb convert | [nb4,nb4+eb) (col,type) histogram | [..,+128) wpk ----
__global__ __launch_bounds__(256) void k_prep(const float* __restrict__ x, unsigned short* __restrict__ xb, int n4,
                                              const int* __restrict__ col, const int* __restrict__ et, int E,
                                              int* __restrict__ cnt8, int nb4, int eb,
                                              const float* __restrict__ W1, const float* __restrict__ W2,
                                              unsigned short* __restrict__ wpk){
    int blk = blockIdx.x;
    if (blk < nb4){
        int i = blk * 256 + threadIdx.x;
        if (i >= n4) return;
        f32x4 v = __builtin_nontemporal_load((const f32x4*)x + i);   // x dead after this read
        uint2 o; o.x = packrn(v.x, v.y); o.y = packrn(v.z, v.w);
        *(uint2*)(xb + (size_t)i * 4) = o;
    } else if (blk < nb4 + eb){
        int e = (blk - nb4) * 256 + threadIdx.x;
        if (e < E) atomicAdd(&cnt8[col[e] * NREL + et[e]], 1);
    } else {
        int b = (blk - nb4 - eb) * 4 + (threadIdx.x >> 6);   // ((slot*8+nt)*4+ks), 512 total
        int lane = threadIdx.x & 63;
        int ks = b & 3, nt = (b >> 2) & 7, slot = b >> 5;
        const float* Wsrc = (slot < 8) ? (W1 + (size_t)slot * DIM * DIM)
                                       : (W2 + (size_t)(slot - 8) * DIM * DIM);
        int k0 = ks * 32 + (lane >> 4) * 8;
        int n  = nt * 16 + (lane & 15);
        uint4 ow;
        ow.x = packrn(Wsrc[(size_t)(k0 + 0) * DIM + n], Wsrc[(size_t)(k0 + 1) * DIM + n]);
        ow.y = packrn(Wsrc[(size_t)(k0 + 2) * DIM + n], Wsrc[(size_t)(k0 + 3) * DIM + n]);
        ow.z = packrn(Wsrc[(size_t)(k0 + 4) * DIM + n], Wsrc[(size_t)(k0 + 5) * DIM + n]);
        ow.w = packrn(Wsrc[(size_t)(k0 + 6) * DIM + n], Wsrc[(size_t)(k0 + 7) * DIM + n]);
        *(uint4*)(wpk + ((size_t)b * 64 + lane) * 8) = ow;
    }
}

// ---- hierarchical exclusive scan of cnt8 (M8 = N*8) -> start8[M8+1], pos8 ----
__global__ __launch_bounds__(256) void k_scan1(const int* __restrict__ cnt, int M, int* __restrict__ bsum){
    int t = threadIdx.x;
    int base = blockIdx.x * SCB + t * 16;
    int s = 0;
    #pragma unroll
    for (int k = 0; k < 16; ++k){
        int i = base + k;
        if (i < M) s += cnt[i];
    }
    #pragma unroll
    for (int o = 1; o < 64; o <<= 1) s += __shfl_xor(s, o);
    __shared__ int wsum[4];
    if ((t & 63) == 0) wsum[t >> 6] = s;
    __syncthreads();
    if (t == 0) bsum[blockIdx.x] = wsum[0] + wsum[1] + wsum[2] + wsum[3];
}

// scan3: absorbs old scan2 (per-wave redundant bsum prefix) AND emits deginv[c]
__global__ __launch_bounds__(256) void k_scan3(const int* __restrict__ cnt, int M,
                                               const int* __restrict__ bsum, int NBS,
                                               int* __restrict__ startArr, int* __restrict__ pos,
                                               float* __restrict__ deginv){
    int t = threadIdx.x;
    int base = blockIdx.x * SCB + t * 16;
    int vals[16];
    int s = 0;
    #pragma unroll
    for (int k = 0; k < 16; ++k){
        int i = base + k;
        vals[k] = (i < M) ? cnt[i] : 0;
        s += vals[k];
    }

    {
        int d0 = 0, d1 = 0;
        #pragma unroll
        for (int k = 0; k < 8; ++k){ d0 += vals[k]; d1 += vals[8 + k]; }
        int c0i = base >> 3;
        if (base < M)     deginv[c0i]     = d0 > 0 ? rsqrtf((float)d0) : 0.f;
        if (base + 8 < M) deginv[c0i + 1] = d1 > 0 ? rsqrtf((float)d1) : 0.f;
    }

    int lane = t & 63, w = t >> 6;

    int bp = 0, tp = 0;
    for (int i = lane; i < NBS; i += 64){
        int bv = bsum[i];
        if (i < (int)blockIdx.x) bp += bv;
        tp += bv;
    }
    #pragma unroll
    for (int o = 1; o < 64; o <<= 1){ bp += __shfl_xor(bp, o); tp += __shfl_xor(tp, o); }

    int v = s;
    #pragma unroll
    for (int o = 1; o < 64; o <<= 1){
        int u = __shfl_up(v, o);
        if (lane >= o) v += u;
    }
    __shared__ int wsum[4];
    if (lane == 63) wsum[w] = v;
    __syncthreads();
    int excl = v - s + bp;
    for (int i = 0; i < w; ++i) excl += wsum[i];
    #pragma unroll
    for (int k = 0; k < 16; ++k){
        int i = base + k;
        if (i < M){ startArr[i] = excl; pos[i] = excl; excl += vals[k]; }
    }
    if (blockIdx.x == (unsigned)(gridDim.x - 1) && t == 0) startArr[M] = tp;
}

// ---- place edges sorted by (col,type); coef inline ----
// meta x = cl<<28 | type<<25 | row   (row < 2^17; run key = top 7 bits)
__global__ __launch_bounds__(256) void k_place(const int* __restrict__ row, const int* __restrict__ col,
                                               const int* __restrict__ et, const float* __restrict__ ew,
                                               const float* __restrict__ deginv,
                                               int E, int* __restrict__ pos8, int2* __restrict__ pkm){
    int e = blockIdx.x * 256 + threadIdx.x;
    if (e >= E) return;
    int r = row[e], c = col[e], t = et[e];
    float cf = deginv[r] * deginv[c] * ew[e];
    int p = atomicAdd(&pos8[(c << 3) + t], 1);
    union { float f; int i; } cv; cv.f = cf;
    pkm[p] = make_int2(((c & (CPB - 1)) << 28) | (t << 25) | r, cv.i);
}

// ---- fused aggregate + transform conv : PERSISTENT + SOFTWARE-PIPELINED ----
// 1024 persistent blocks x 512 thr; each block loops over ~6 tiles of 16 cols.
// Per iteration: [issue HBM gathers for tile t+1] [MFMA tile t — gathers drain
// underneath] [epilogue: C frags into buf + re-zero buf] [PROC+flush t+1 into buf].
// The random-gather HBM latency (the invariant ~90us limiter, rounds 0-6) leaves the
// critical path; only the prologue exposes it once per block.
template<int MODE>
__global__ __launch_bounds__(512, 8) void k_fused(const unsigned short* __restrict__ xbin,
                                                  const unsigned short* __restrict__ wpk,
                                                  const int* __restrict__ cs8,
                                                  const int2* __restrict__ pkm,
                                                  const float* __restrict__ bias,
                                                  unsigned short* __restrict__ zb,
                                                  const unsigned short* __restrict__ xb2,
                                                  const unsigned short* __restrict__ z1b2,
                                                  float* __restrict__ outS,
                                                  float* __restrict__ outH,
                                                  int N, int NT, int wslot){
    __shared__ unsigned short s[CPB * 1024];    // 32 KB: bf16 A-tile / fp32 out-tile
    int tid = threadIdx.x;
    int wid = tid >> 6, lane = tid & 63;
    const int stride = gridDim.x;
    const int* __restrict__ mp = (const int*)pkm;

    uint4 z4v = {0u, 0u, 0u, 0u};
    #pragma unroll
    for (int k = 0; k < 4; ++k) ((uint4*)s)[tid + 512 * k] = z4v;
    __syncthreads();

#define FLUSH() *(uint32_t*)((char*)s + flushByte) = packrn(a0, a1)
#define PROC(mx, cf, u) do{                                                       \
        int fk_ = (int)(((unsigned)(mx)) >> 25);                                  \
        if (fk_ != fkPrev){                                                       \
            if (fkPrev >= 0) FLUSH();                                             \
            fkPrev = fk_;                                                         \
            flushByte = (fk_ << 8) + ((lane << 2) ^ ((fk_ << 1) & 0x70));         \
            a0 = 0.f; a1 = 0.f;                                                   \
        }                                                                         \
        a0 = fmaf(cf, bf2f((u) & 0xFFFFu), a0);                                   \
        a1 = fmaf(cf, bf2f((u) >> 16),     a1); }while(0)
#define XROW(mx) ((const uint32_t*)xbin)[((size_t)(((mx) & 0x1FFFF) << 6)) + lane]

    int t0 = blockIdx.x;
    if (t0 >= NT) return;

    // ---- prologue: full phase 1 for tile t0 (one exposed gather latency per block) ----
    {
        int c = t0 * CPB + wid * 2;
        if (c < N){
            int cHi = c + 2; if (cHi > N) cHi = N;
            int e  = __builtin_amdgcn_readfirstlane(cs8[c * NREL]);
            int eE = __builtin_amdgcn_readfirstlane(cs8[cHi * NREL]);
            int fkPrev = -1, flushByte = 0;
            float a0 = 0.f, a1 = 0.f;
            while (e < eE){
                int n = eE - e; if (n > 16) n = 16;
                int mxs[16]; float cfs[16]; uint32_t u[16];
                int mprev = 0;
                #pragma unroll
                for (int k = 0; k < 16; ++k){
                    int live = k < n;
                    int raw  = mp[2 * (e + k)];
                    float rc = asf(mp[2 * (e + k) + 1]);
                    int mx = (k == 0) ? raw : (live ? raw : mprev);
                    mxs[k] = mx; mprev = mx;
                    cfs[k] = live ? rc : 0.f;
                }
                #pragma unroll
                for (int k = 0; k < 16; ++k) u[k] = XROW(mxs[k]);
                __builtin_amdgcn_sched_barrier(0);
                #pragma unroll
                for (int k = 0; k < 16; ++k) PROC(mxs[k], cfs[k], u[k]);
                e += n;
            }
            if (fkPrev >= 0) FLUSH();
        }
    }
    __syncthreads();

    int al = lane & 15, ak2 = (lane >> 4) * 16;
    int swz = (al & 7) << 4;
    const char* rowA = (const char*)s + al * 2048;
    const short8* bbase = (const short8*)wpk + (size_t)wslot * 2048 + lane;
    float* ot = (float*)s;
    int nt = wid, crb = (lane >> 4) * 4, dcl = lane & 15;

    for (int t = t0; t < NT; t += stride){
        int nxt = t + stride;
        bool hasN = nxt < NT;

        // ---- stage 1: issue gather batch for tile nxt (metas scalar, rows vector) ----
        int n0 = 0, ge = 0, geE = 0;
        int gmx[16]; float gcf[16]; uint32_t gu[16];
        if (hasN){
            int c = nxt * CPB + wid * 2;
            if (c < N){
                int cHi = c + 2; if (cHi > N) cHi = N;
                ge  = __builtin_amdgcn_readfirstlane(cs8[c * NREL]);
                geE = __builtin_amdgcn_readfirstlane(cs8[cHi * NREL]);
                n0 = geE - ge; if (n0 > 16) n0 = 16;
                if (n0 > 0){
                    int mprev = 0;
                    #pragma unroll
                    for (int k = 0; k < 16; ++k){
                        int live = k < n0;
                        int raw  = mp[2 * (ge + k)];
                        float rc = asf(mp[2 * (ge + k) + 1]);
                        int mx = (k == 0) ? raw : (live ? raw : mprev);
                        gmx[k] = mx; mprev = mx;
                        gcf[k] = live ? rc : 0.f;
                    }
                    #pragma unroll
                    for (int k = 0; k < 16; ++k) gu[k] = XROW(gmx[k]);   // in flight across compute
                    ge += n0;
                }
            }
        }

        // ---- stage 2: MFMA tile t (gathers drain underneath) ----
        f32x4 acc = (f32x4){0,0,0,0};
        __builtin_amdgcn_s_setprio(1);
        #pragma unroll 4
        for (int ksg = 0; ksg < 32; ++ksg){
            int off = (ksg * 64 + ak2) ^ swz;
            short8 A = *(const short8*)(rowA + off);
            int tt = ksg >> 2, ksl = ksg & 3;
            short8 B = (bbase + (size_t)tt * 2048)[(nt * 4 + ksl) * 64];
            acc = __builtin_amdgcn_mfma_f32_16x16x32_bf16(A, B, acc, 0, 0, 0);
        }
        __builtin_amdgcn_s_setprio(0);
        __syncthreads();   // bar_B: all A-reads done; gathers retired (implicit vmcnt(0))

        // ---- stage 3: C frags -> buf[0,8K) + zero buf[8K,32K) ----
        {
            int d = nt * 16 + dcl;
            float bv = bias[d];
            #pragma unroll
            for (int r = 0; r < 4; ++r){
                float v = acc[r] + bv;
                if (MODE == 0) v = fmaxf(v, 0.f);
                ot[(crb + r) * DIM + d] = v;
            }
            uint4* zp = (uint4*)((char*)s + 8192);
            #pragma unroll
            for (int k = 0; k < 3; ++k) zp[tid + 512 * k] = z4v;
        }
        __syncthreads();   // bar_C

        // ---- stage 4: coalesced stores + self-zero of [0,8K) ----
        {
            f32x4 zf = (f32x4){0,0,0,0};
            if (MODE == 0){
                if (tid < 256){
                    int rowi = tid >> 4, seg = tid & 15;
                    int c = t * CPB + rowi;
                    float* src = ot + rowi * DIM + seg * 8;
                    if (c < N){
                        uint4 vv;
                        vv.x = packrn(src[0], src[1]);
                        vv.y = packrn(src[2], src[3]);
                        vv.z = packrn(src[4], src[5]);
                        vv.w = packrn(src[6], src[7]);
                        *(uint4*)(zb + ((size_t)c << 7) + seg * 8) = vv;
                    }
                    *(f32x4*)src = zf;
                    *(f32x4*)(src + 4) = zf;
                }
            } else {
                int rowi = tid >> 5, q = tid & 31;
                int c = t * CPB + rowi;
                int d0 = q * 4;
                float* src = ot + rowi * DIM + d0;
                if (c < N){
                    size_t o = ((size_t)c << 7) + d0;
                    ushort4 xv4 = *(const ushort4*)(xb2 + o);
                    ushort4 zv4 = *(const ushort4*)(z1b2 + o);
                    f32x4 S, H;
                    {
                        float xv = bf2f(xv4.x), z1 = bf2f(zv4.x), v = src[0];
                        S.x = (xv + z1 + v) * 0.25f; H.x = (z1 + v) * (1.0f / 3.0f);
                    }
                    {
                        float xv = bf2f(xv4.y), z1 = bf2f(zv4.y), v = src[1];
                        S.y = (xv + z1 + v) * 0.25f; H.y = (z1 + v) * (1.0f / 3.0f);
                    }
                    {
                        float xv = bf2f(xv4.z), z1 = bf2f(zv4.z), v = src[2];
                        S.z = (xv + z1 + v) * 0.25f; H.z = (z1 + v) * (1.0f / 3.0f);
                    }
                    {
                        float xv = bf2f(xv4.w), z1 = bf2f(zv4.w), v = src[3];
                        S.w = (xv + z1 + v) * 0.25f; H.w = (z1 + v) * (1.0f / 3.0f);
                    }
                    __builtin_nontemporal_store(S, (f32x4*)(outS + o));
                    __builtin_nontemporal_store(H, (f32x4*)(outH + o));
                }
                *(f32x4*)src = zf;
            }
        }
        __syncthreads();   // bar_D: buf fully zeroed, store-reads complete

        // ---- stage 5: PROC + flush tile nxt into buf ----
        if (hasN){
            int c = nxt * CPB + wid * 2;
            if (c < N && n0 > 0){
                int fkPrev = -1, flushByte = 0;
                float a0 = 0.f, a1 = 0.f;
                #pragma unroll
                for (int k = 0; k < 16; ++k) PROC(gmx[k], gcf[k], gu[k]);
                while (ge < geE){                      // rare extra batches (n>16)
                    int n = geE - ge; if (n > 16) n = 16;
                    int mxs[16]; float cfs[16]; uint32_t u[16];
                    int mprev = 0;
                    #pragma unroll
                    for (int k = 0; k < 16; ++k){
                        int live = k < n;
                        int raw  = mp[2 * (ge + k)];
                        float rc = asf(mp[2 * (ge + k) + 1]);
                        int mx = (k == 0) ? raw : (live ? raw : mprev);
                        mxs[k] = mx; mprev = mx;
                        cfs[k] = live ? rc : 0.f;
                    }
                    #pragma unroll
                    for (int k = 0; k < 16; ++k) u[k] = XROW(mxs[k]);
                    __builtin_amdgcn_sched_barrier(0);
                    #pragma unroll
                    for (int k = 0; k < 16; ++k) PROC(mxs[k], cfs[k], u[k]);
                    ge += n;
                }
                if (fkPrev >= 0) FLUSH();
            }
        }
        __syncthreads();   // bar_A: A-tile(nxt) ready
    }
#undef PROC
#undef FLUSH
#undef XROW
}

extern "C" void kernel_launch(void* const* d_in, const int* in_sizes, int n_in,
                              void* d_out, int out_size, void* d_ws, size_t ws_size,
                              hipStream_t stream) {
    const float* x  = (const float*)d_in[0];
    const int*   ei = (const int*)d_in[1];
    const int*   et = (const int*)d_in[2];
    const float* ew = (const float*)d_in[3];
    const float* W1 = (const float*)d_in[4];
    const float* b1 = (const float*)d_in[5];
    const float* W2 = (const float*)d_in[6];
    const float* b2 = (const float*)d_in[7];

    int E = in_sizes[2];
    int N = in_sizes[0] / DIM;
    const int* row = ei;
    const int* col = ei + E;

    float* out = (float*)d_out;
    int ND  = N * DIM;
    int ND4 = ND / 4;
    float* zS = out;        // slot 0: z_star
    float* zH = out + ND;   // slot 1: z_sharp

    int M8   = N * NREL;
    int NBS8 = cdiv(M8, SCB);

    // ---- workspace carve (~70 MB) ----
    char* wsb = (char*)d_ws;
    size_t off = 0;
    auto take = [&](size_t bytes) -> char* {
        char* p = wsb + off;
        off = (off + bytes + 255) & ~(size_t)255;
        return p;
    };
    int*            cnt8     = (int*)           take((size_t)M8 * 4);
    int*            start8   = (int*)           take(((size_t)M8 + 1) * 4);
    int*            pos8     = (int*)           take((size_t)M8 * 4);
    int*            bsum     = (int*)           take(((size_t)NBS8 + 1) * 4);
    float*          deginv   = (float*)         take((size_t)N * 4);
    int2*           pkm      = (int2*)          take(((size_t)E + 16) * 8);       // +16: batch overread pad
    unsigned short* wpk      = (unsigned short*)take((size_t)16 * 2048 * 8 * 2);  // 512 KB
    unsigned short* xb       = (unsigned short*)take((size_t)ND * 2);
    unsigned short* z1b      = (unsigned short*)take((size_t)ND * 2);
    (void)n_in; (void)out_size; (void)ws_size;

    (void)hipMemsetAsync(cnt8, 0, (size_t)M8 * 4, stream);

    int eb  = cdiv(E, 256);
    int nb4 = cdiv(ND4, 256);
    k_prep  <<<nb4 + eb + 128, 256, 0, stream>>>(x, xb, ND4, col, et, E, cnt8, nb4, eb, W1, W2, wpk);
    k_scan1 <<<NBS8, 256, 0, stream>>>(cnt8, M8, bsum);
    k_scan3 <<<NBS8, 256, 0, stream>>>(cnt8, M8, bsum, NBS8, start8, pos8, deginv);
    k_place <<<eb, 256, 0, stream>>>(row, col, et, ew, deginv, E, pos8, pkm);

    int fb = cdiv(N, CPB);
    int pg = 1024;                 // persistent grid: 4 blocks/CU x 256 CUs
    if (pg > fb) pg = fb;
    // conv1: z1b = bf16(relu(agg(x) @ W1 + b1))
    k_fused<0><<<pg, 512, 0, stream>>>(xb, wpk, start8, pkm, b1, z1b, nullptr, nullptr, nullptr, nullptr, N, fb, 0);
    // conv2: fused z_star/z_sharp from xb, z1b, agg(z1b) @ W2 + b2
    k_fused<1><<<pg, 512, 0, stream>>>(z1b, wpk, start8, pkm, b2, nullptr, xb, z1b, zS, zH, N, fb, 8);
}

// Round 8
// 283.895 us; speedup vs baseline: 2.2896x; 2.2896x over previous
//
#include <hip/hip_runtime.h>
#include <hip/hip_bf16.h>
#include <cstdint>
#include <cstddef>

#define DIM  128
#define NREL 8
#define SCB  4096   // elements per scan block (16 per thread)
#define CPB  16     // cols per fused block (32 KB LDS, 512-thr blocks -> 4 blocks/CU = 32 waves)

typedef __attribute__((ext_vector_type(8))) short short8;
typedef __attribute__((ext_vector_type(4))) float f32x4;

static inline int cdiv(int a, int b){ return (a + b - 1) / b; }

// single-instruction packed fp32x2 -> bf16x2 (RNE)
__device__ inline uint32_t packrn(float lo, float hi){
    __hip_bfloat162 h = __float22bfloat162_rn(make_float2(lo, hi));
    union { __hip_bfloat162 h; uint32_t u; } v; v.h = h; return v.u;
}
__device__ inline float bf2f(uint32_t lo16){
    union { uint32_t u; float f; } v; v.u = lo16 << 16; return v.f;
}
__device__ inline float asf(int u){
    union { int i; float f; } v; v.i = u; return v.f;
}

// ---- fused prep: [0,nb4) xb convert | [nb4,nb4+eb) (col,type) histogram | [..,+128) wpk ----
__global__ __launch_bounds__(256) void k_prep(const float* __restrict__ x, unsigned short* __restrict__ xb, int n4,
                                              const int* __restrict__ col, const int* __restrict__ et, int E,
                                              int* __restrict__ cnt8, int nb4, int eb,
                                              const float* __restrict__ W1, const float* __restrict__ W2,
                                              unsigned short* __restrict__ wpk){
    int blk = blockIdx.x;
    if (blk < nb4){
        int i = blk * 256 + threadIdx.x;
        if (i >= n4) return;
        f32x4 v = __builtin_nontemporal_load((const f32x4*)x + i);   // x dead after this read
        uint2 o; o.x = packrn(v.x, v.y); o.y = packrn(v.z, v.w);
        *(uint2*)(xb + (size_t)i * 4) = o;
    } else if (blk < nb4 + eb){
        int e = (blk - nb4) * 256 + threadIdx.x;
        if (e < E) atomicAdd(&cnt8[col[e] * NREL + et[e]], 1);
    } else {
        int b = (blk - nb4 - eb) * 4 + (threadIdx.x >> 6);   // ((slot*8+nt)*4+ks), 512 total
        int lane = threadIdx.x & 63;
        int ks = b & 3, nt = (b >> 2) & 7, slot = b >> 5;
        const float* Wsrc = (slot < 8) ? (W1 + (size_t)slot * DIM * DIM)
                                       : (W2 + (size_t)(slot - 8) * DIM * DIM);
        int k0 = ks * 32 + (lane >> 4) * 8;
        int n  = nt * 16 + (lane & 15);
        uint4 ow;
        ow.x = packrn(Wsrc[(size_t)(k0 + 0) * DIM + n], Wsrc[(size_t)(k0 + 1) * DIM + n]);
        ow.y = packrn(Wsrc[(size_t)(k0 + 2) * DIM + n], Wsrc[(size_t)(k0 + 3) * DIM + n]);
        ow.z = packrn(Wsrc[(size_t)(k0 + 4) * DIM + n], Wsrc[(size_t)(k0 + 5) * DIM + n]);
        ow.w = packrn(Wsrc[(size_t)(k0 + 6) * DIM + n], Wsrc[(size_t)(k0 + 7) * DIM + n]);
        *(uint4*)(wpk + ((size_t)b * 64 + lane) * 8) = ow;
    }
}

// ---- hierarchical exclusive scan of cnt8 (M8 = N*8) -> start8[M8+1], pos8 ----
__global__ __launch_bounds__(256) void k_scan1(const int* __restrict__ cnt, int M, int* __restrict__ bsum){
    int t = threadIdx.x;
    int base = blockIdx.x * SCB + t * 16;
    int s = 0;
    #pragma unroll
    for (int k = 0; k < 16; ++k){
        int i = base + k;
        if (i < M) s += cnt[i];
    }
    #pragma unroll
    for (int o = 1; o < 64; o <<= 1) s += __shfl_xor(s, o);
    __shared__ int wsum[4];
    if ((t & 63) == 0) wsum[t >> 6] = s;
    __syncthreads();
    if (t == 0) bsum[blockIdx.x] = wsum[0] + wsum[1] + wsum[2] + wsum[3];
}

// scan3: absorbs old scan2 (per-wave redundant bsum prefix) AND emits deginv[c]
__global__ __launch_bounds__(256) void k_scan3(const int* __restrict__ cnt, int M,
                                               const int* __restrict__ bsum, int NBS,
                                               int* __restrict__ startArr, int* __restrict__ pos,
                                               float* __restrict__ deginv){
    int t = threadIdx.x;
    int base = blockIdx.x * SCB + t * 16;
    int vals[16];
    int s = 0;
    #pragma unroll
    for (int k = 0; k < 16; ++k){
        int i = base + k;
        vals[k] = (i < M) ? cnt[i] : 0;
        s += vals[k];
    }

    {
        int d0 = 0, d1 = 0;
        #pragma unroll
        for (int k = 0; k < 8; ++k){ d0 += vals[k]; d1 += vals[8 + k]; }
        int c0i = base >> 3;
        if (base < M)     deginv[c0i]     = d0 > 0 ? rsqrtf((float)d0) : 0.f;
        if (base + 8 < M) deginv[c0i + 1] = d1 > 0 ? rsqrtf((float)d1) : 0.f;
    }

    int lane = t & 63, w = t >> 6;

    int bp = 0, tp = 0;
    for (int i = lane; i < NBS; i += 64){
        int bv = bsum[i];
        if (i < (int)blockIdx.x) bp += bv;
        tp += bv;
    }
    #pragma unroll
    for (int o = 1; o < 64; o <<= 1){ bp += __shfl_xor(bp, o); tp += __shfl_xor(tp, o); }

    int v = s;
    #pragma unroll
    for (int o = 1; o < 64; o <<= 1){
        int u = __shfl_up(v, o);
        if (lane >= o) v += u;
    }
    __shared__ int wsum[4];
    if (lane == 63) wsum[w] = v;
    __syncthreads();
    int excl = v - s + bp;
    for (int i = 0; i < w; ++i) excl += wsum[i];
    #pragma unroll
    for (int k = 0; k < 16; ++k){
        int i = base + k;
        if (i < M){ startArr[i] = excl; pos[i] = excl; excl += vals[k]; }
    }
    if (blockIdx.x == (unsigned)(gridDim.x - 1) && t == 0) startArr[M] = tp;
}

// ---- place edges sorted by (col,type); coef inline ----
// meta x = cl<<28 | type<<25 | row   (row < 2^17; run key = top 7 bits)
__global__ __launch_bounds__(256) void k_place(const int* __restrict__ row, const int* __restrict__ col,
                                               const int* __restrict__ et, const float* __restrict__ ew,
                                               const float* __restrict__ deginv,
                                               int E, int* __restrict__ pos8, int2* __restrict__ pkm){
    int e = blockIdx.x * 256 + threadIdx.x;
    if (e >= E) return;
    int r = row[e], c = col[e], t = et[e];
    float cf = deginv[r] * deginv[c] * ew[e];
    int p = atomicAdd(&pos8[(c << 3) + t], 1);
    union { float f; int i; } cv; cv.f = cf;
    pkm[p] = make_int2(((c & (CPB - 1)) << 28) | (t << 25) | r, cv.i);
}

// ---- fused aggregate + transform conv ----
// out[c] = bias + sum_t ( sum_{e: col=c, type=t} coef_e * x[row_e] ) @ W[t]
// 512 threads = 8 waves; block owns 16 cols; 32 KB LDS -> 4 blocks/CU = 32 waves/CU.
// Phase 1 (DYNAMIC round-robin, run-ownership by start batch): the block's whole
//   sorted edge range is cut into 16-edge batches; wave w claims batches w, w+8, ...
//   A wave skips leading edges whose run started in the previous batch, and extends
//   through its last run's tail — every (cl,type) run is processed WHOLLY by exactly
//   one wave, so the overwrite-flush stays exact (no atomics, no extra rounding).
//   This removes the static col->wave straggler (max-of-8 Poisson) that pinned every
//   previous variant at ~90us: block phase-1 time ~= mean, not max.
// Phase 2: wave nt=wid owns one 16x16 N-slice, full K=1024; B streamed from L2;
//   setprio(1) around MFMA cluster.
// Epilogue via LDS fp32 tile (reuse) -> coalesced stores.
template<int MODE>
__global__ __launch_bounds__(512, 8) void k_fused(const unsigned short* __restrict__ xbin,
                                                  const unsigned short* __restrict__ wpk,
                                                  const int* __restrict__ cs8,
                                                  const int2* __restrict__ pkm,
                                                  const float* __restrict__ bias,
                                                  unsigned short* __restrict__ zb,
                                                  const unsigned short* __restrict__ xb2,
                                                  const unsigned short* __restrict__ z1b2,
                                                  float* __restrict__ outS,
                                                  float* __restrict__ outH,
                                                  int N, int wslot){
    __shared__ unsigned short s[CPB * 1024];    // 32 KB: bf16 A-tile, then fp32 out-tile
    int tid = threadIdx.x;
    int wid = tid >> 6, lane = tid & 63;
    int c0 = blockIdx.x * CPB;

    // zero the A-tile (2048 uint4 / 512 threads)
    uint4 z4 = {0u, 0u, 0u, 0u};
    #pragma unroll
    for (int k = 0; k < 4; ++k) ((uint4*)s)[tid + 512 * k] = z4;
    __syncthreads();

#define FLUSH() *(uint32_t*)((char*)s + flushByte) = packrn(a0, a1)
#define PROC(mx, cf, u) do{                                                       \
        int fk_ = (int)(((unsigned)(mx)) >> 25);                                  \
        if (fk_ != fkPrev){                                                       \
            if (fkPrev >= 0) FLUSH();                                             \
            fkPrev = fk_;                                                         \
            flushByte = (fk_ << 8) + ((lane << 2) ^ ((fk_ << 1) & 0x70));         \
            a0 = 0.f; a1 = 0.f;                                                   \
        }                                                                         \
        a0 = fmaf(cf, bf2f((u) & 0xFFFFu), a0);                                   \
        a1 = fmaf(cf, bf2f((u) >> 16),     a1); }while(0)
#define XROW(mx) ((const uint32_t*)xbin)[((size_t)(((mx) & 0x1FFFF) << 6)) + lane]

    // ---- phase 1: dynamic 16-edge batches over the block's full edge range ----
    {
        int cHi = c0 + CPB; if (cHi > N) cHi = N;
        int e0 = __builtin_amdgcn_readfirstlane(cs8[c0 * NREL]);
        int eT = __builtin_amdgcn_readfirstlane(cs8[cHi * NREL]);
        int fkPrev = -1, flushByte = 0;
        float a0 = 0.f, a1 = 0.f;
        const int* __restrict__ mp = (const int*)pkm;   // uniform -> s_load path

        for (int b0 = e0 + wid * 16; b0 < eT; b0 += 8 * 16){
            int bE = b0 + 16; if (bE > eT) bE = eT;
            int sb = b0;
            if (b0 > e0){                                  // skip leading run-continuation
                unsigned kp = ((unsigned)mp[2 * (b0 - 1)]) >> 25;
                while (sb < bE && (((unsigned)mp[2 * sb]) >> 25) == kp) ++sb;
            }
            if (sb >= bE) continue;                        // whole batch was continuation
            int tE = bE;
            {                                              // extend through last run's tail
                unsigned kl = ((unsigned)mp[2 * (bE - 1)]) >> 25;
                while (tE < eT && (((unsigned)mp[2 * tE]) >> 25) == kl) ++tE;
            }
            while (sb < tE){
                int n = tE - sb; if (n > 16) n = 16;
                int mxs[16]; float cfs[16]; uint32_t u[16];
                int mprev = 0;
                #pragma unroll
                for (int k = 0; k < 16; ++k){
                    int live = k < n;                      // wave-uniform
                    int raw  = mp[2 * (sb + k)];           // pkm padded +16
                    float rc = asf(mp[2 * (sb + k) + 1]);
                    int mx = (k == 0) ? raw : (live ? raw : mprev);
                    mxs[k] = mx; mprev = mx;
                    cfs[k] = live ? rc : 0.f;              // dead slot: same run key, zero coef
                }
                #pragma unroll
                for (int k = 0; k < 16; ++k) u[k] = XROW(mxs[k]);
                __builtin_amdgcn_sched_barrier(0);
                #pragma unroll
                for (int k = 0; k < 16; ++k) PROC(mxs[k], cfs[k], u[k]);
                sb += n;
            }
        }
        if (fkPrev >= 0) FLUSH();
    }
#undef PROC
#undef FLUSH
#undef XROW
    __syncthreads();

    // ---- phase 2: wave nt=wid: one 16(rows) x 16(dims) tile, K=1024 ----
    int nt = wid;
    f32x4 acc = (f32x4){0,0,0,0};

    int al = lane & 15, ak2 = (lane >> 4) * 16;
    int swz = (al & 7) << 4;
    const char* rowA = (const char*)s + al * 2048;

    const short8* bbase = (const short8*)wpk + (size_t)wslot * 2048 + lane;

    __builtin_amdgcn_s_setprio(1);
    #pragma unroll 4
    for (int ksg = 0; ksg < 32; ++ksg){
        int off = (ksg * 64 + ak2) ^ swz;
        short8 A = *(const short8*)(rowA + off);
        int t = ksg >> 2, ksl = ksg & 3;
        short8 B = (bbase + (size_t)t * 2048)[(nt * 4 + ksl) * 64];
        acc = __builtin_amdgcn_mfma_f32_16x16x32_bf16(A, B, acc, 0, 0, 0);
    }
    __builtin_amdgcn_s_setprio(0);
    __syncthreads();   // all A-reads done; reuse s as fp32 out-tile

    // ---- stage C tile to LDS (bias + relu applied here) ----
    float* ot = (float*)s;   // [CPB][128]
    int crb = (lane >> 4) * 4, dcl = lane & 15;
    {
        int d = nt * 16 + dcl;
        float bv = bias[d];
        #pragma unroll
        for (int r = 0; r < 4; ++r){
            int mrow = crb + r;
            float v = acc[r] + bv;
            if (MODE == 0) v = fmaxf(v, 0.f);
            ot[mrow * DIM + d] = v;
        }
    }
    __syncthreads();

    // ---- coalesced output ----
    if (MODE == 0){
        if (tid < 256){
            int rowi = tid >> 4, seg = tid & 15;
            int c = c0 + rowi;
            if (c < N){
                const float* src = ot + rowi * DIM + seg * 8;
                uint4 vv;
                vv.x = packrn(src[0], src[1]);
                vv.y = packrn(src[2], src[3]);
                vv.z = packrn(src[4], src[5]);
                vv.w = packrn(src[6], src[7]);
                *(uint4*)(zb + ((size_t)c << 7) + seg * 8) = vv;
            }
        }
    } else {
        int rowi = tid >> 5, q = tid & 31;
        int c = c0 + rowi;
        if (c < N){
            int d0 = q * 4;
            size_t o = ((size_t)c << 7) + d0;
            ushort4 xv4 = *(const ushort4*)(xb2 + o);
            ushort4 zv4 = *(const ushort4*)(z1b2 + o);
            const float* src = ot + rowi * DIM + d0;
            f32x4 S, H;
            {
                float xv = bf2f(xv4.x), z1 = bf2f(zv4.x), v = src[0];
                S.x = (xv + z1 + v) * 0.25f; H.x = (z1 + v) * (1.0f / 3.0f);
            }
            {
                float xv = bf2f(xv4.y), z1 = bf2f(zv4.y), v = src[1];
                S.y = (xv + z1 + v) * 0.25f; H.y = (z1 + v) * (1.0f / 3.0f);
            }
            {
                float xv = bf2f(xv4.z), z1 = bf2f(zv4.z), v = src[2];
                S.z = (xv + z1 + v) * 0.25f; H.z = (z1 + v) * (1.0f / 3.0f);
            }
            {
                float xv = bf2f(xv4.w), z1 = bf2f(zv4.w), v = src[3];
                S.w = (xv + z1 + v) * 0.25f; H.w = (z1 + v) * (1.0f / 3.0f);
            }
            __builtin_nontemporal_store(S, (f32x4*)(outS + o));
            __builtin_nontemporal_store(H, (f32x4*)(outH + o));
        }
    }
}

extern "C" void kernel_launch(void* const* d_in, const int* in_sizes, int n_in,
                              void* d_out, int out_size, void* d_ws, size_t ws_size,
                              hipStream_t stream) {
    const float* x  = (const float*)d_in[0];
    const int*   ei = (const int*)d_in[1];
    const int*   et = (const int*)d_in[2];
    const float* ew = (const float*)d_in[3];
    const float* W1 = (const float*)d_in[4];
    const float* b1 = (const float*)d_in[5];
    const float* W2 = (const float*)d_in[6];
    const float* b2 = (const float*)d_in[7];

    int E = in_sizes[2];
    int N = in_sizes[0] / DIM;
    const int* row = ei;
    const int* col = ei + E;

    float* out = (float*)d_out;
    int ND  = N * DIM;
    int ND4 = ND / 4;
    float* zS = out;        // slot 0: z_star
    float* zH = out + ND;   // slot 1: z_sharp

    int M8   = N * NREL;
    int NBS8 = cdiv(M8, SCB);

    // ---- workspace carve (~70 MB) ----
    char* wsb = (char*)d_ws;
    size_t off = 0;
    auto take = [&](size_t bytes) -> char* {
        char* p = wsb + off;
        off = (off + bytes + 255) & ~(size_t)255;
        return p;
    };
    int*            cnt8     = (int*)           take((size_t)M8 * 4);
    int*            start8   = (int*)           take(((size_t)M8 + 1) * 4);
    int*            pos8     = (int*)           take((size_t)M8 * 4);
    int*            bsum     = (int*)           take(((size_t)NBS8 + 1) * 4);
    float*          deginv   = (float*)         take((size_t)N * 4);
    int2*           pkm      = (int2*)          take(((size_t)E + 16) * 8);       // +16: batch overread pad
    unsigned short* wpk      = (unsigned short*)take((size_t)16 * 2048 * 8 * 2);  // 512 KB
    unsigned short* xb       = (unsigned short*)take((size_t)ND * 2);
    unsigned short* z1b      = (unsigned short*)take((size_t)ND * 2);
    (void)n_in; (void)out_size; (void)ws_size;

    (void)hipMemsetAsync(cnt8, 0, (size_t)M8 * 4, stream);

    int eb  = cdiv(E, 256);
    int nb4 = cdiv(ND4, 256);
    k_prep  <<<nb4 + eb + 128, 256, 0, stream>>>(x, xb, ND4, col, et, E, cnt8, nb4, eb, W1, W2, wpk);
    k_scan1 <<<NBS8, 256, 0, stream>>>(cnt8, M8, bsum);
    k_scan3 <<<NBS8, 256, 0, stream>>>(cnt8, M8, bsum, NBS8, start8, pos8, deginv);
    k_place <<<eb, 256, 0, stream>>>(row, col, et, ew, deginv, E, pos8, pkm);

    int fb = cdiv(N, CPB);
    // conv1: z1b = bf16(relu(agg(x) @ W1 + b1))
    k_fused<0><<<fb, 512, 0, stream>>>(xb, wpk, start8, pkm, b1, z1b, nullptr, nullptr, nullptr, nullptr, N, 0);
    // conv2: fused z_star/z_sharp from xb, z1b, agg(z1b) @ W2 + b2
    k_fused<1><<<fb, 512, 0, stream>>>(z1b, wpk, start8, pkm, b2, nullptr, xb, z1b, zS, zH, N, 8);
}

// Round 9
// 246.120 us; speedup vs baseline: 2.6410x; 1.1535x over previous
//
#include <hip/hip_runtime.h>
#include <hip/hip_bf16.h>
#include <cstdint>
#include <cstddef>

#define DIM  128
#define NREL 8
#define SCB  4096   // elements per scan block (16 per thread)
#define CPB  20     // cols per fused block (40 KB LDS x 4 blocks/CU = 160 KB exactly)

typedef __attribute__((ext_vector_type(8))) short short8;
typedef __attribute__((ext_vector_type(4))) float f32x4;

static inline int cdiv(int a, int b){ return (a + b - 1) / b; }

// single-instruction packed fp32x2 -> bf16x2 (RNE)
__device__ inline uint32_t packrn(float lo, float hi){
    __hip_bfloat162 h = __float22bfloat162_rn(make_float2(lo, hi));
    union { __hip_bfloat162 h; uint32_t u; } v; v.h = h; return v.u;
}
__device__ inline float bf2f(uint32_t lo16){
    union { uint32_t u; float f; } v; v.u = lo16 << 16; return v.f;
}
__device__ inline float asf(int u){
    union { int i; float f; } v; v.i = u; return v.f;
}

// ---- fused prep: [0,nb4) xb convert | [nb4,nb4+eb) (col,type) histogram | [..,+128) wpk ----
__global__ __launch_bounds__(256) void k_prep(const float* __restrict__ x, unsigned short* __restrict__ xb, int n4,
                                              const int* __restrict__ col, const int* __restrict__ et, int E,
                                              int* __restrict__ cnt8, int nb4, int eb,
                                              const float* __restrict__ W1, const float* __restrict__ W2,
                                              unsigned short* __restrict__ wpk){
    int blk = blockIdx.x;
    if (blk < nb4){
        int i = blk * 256 + threadIdx.x;
        if (i >= n4) return;
        f32x4 v = __builtin_nontemporal_load((const f32x4*)x + i);   // x dead after this read
        uint2 o; o.x = packrn(v.x, v.y); o.y = packrn(v.z, v.w);
        *(uint2*)(xb + (size_t)i * 4) = o;
    } else if (blk < nb4 + eb){
        int e = (blk - nb4) * 256 + threadIdx.x;
        if (e < E) atomicAdd(&cnt8[col[e] * NREL + et[e]], 1);
    } else {
        int b = (blk - nb4 - eb) * 4 + (threadIdx.x >> 6);   // ((slot*8+nt)*4+ks), 512 total
        int lane = threadIdx.x & 63;
        int ks = b & 3, nt = (b >> 2) & 7, slot = b >> 5;
        const float* Wsrc = (slot < 8) ? (W1 + (size_t)slot * DIM * DIM)
                                       : (W2 + (size_t)(slot - 8) * DIM * DIM);
        int k0 = ks * 32 + (lane >> 4) * 8;
        int n  = nt * 16 + (lane & 15);
        uint4 ow;
        ow.x = packrn(Wsrc[(size_t)(k0 + 0) * DIM + n], Wsrc[(size_t)(k0 + 1) * DIM + n]);
        ow.y = packrn(Wsrc[(size_t)(k0 + 2) * DIM + n], Wsrc[(size_t)(k0 + 3) * DIM + n]);
        ow.z = packrn(Wsrc[(size_t)(k0 + 4) * DIM + n], Wsrc[(size_t)(k0 + 5) * DIM + n]);
        ow.w = packrn(Wsrc[(size_t)(k0 + 6) * DIM + n], Wsrc[(size_t)(k0 + 7) * DIM + n]);
        *(uint4*)(wpk + ((size_t)b * 64 + lane) * 8) = ow;
    }
}

// ---- hierarchical exclusive scan of cnt8 (M8 = N*8) -> start8[M8+1], pos8 ----
__global__ __launch_bounds__(256) void k_scan1(const int* __restrict__ cnt, int M, int* __restrict__ bsum){
    int t = threadIdx.x;
    int base = blockIdx.x * SCB + t * 16;
    int s = 0;
    #pragma unroll
    for (int k = 0; k < 16; ++k){
        int i = base + k;
        if (i < M) s += cnt[i];
    }
    #pragma unroll
    for (int o = 1; o < 64; o <<= 1) s += __shfl_xor(s, o);
    __shared__ int wsum[4];
    if ((t & 63) == 0) wsum[t >> 6] = s;
    __syncthreads();
    if (t == 0) bsum[blockIdx.x] = wsum[0] + wsum[1] + wsum[2] + wsum[3];
}

// scan3: absorbs old scan2 (per-wave redundant bsum prefix) AND emits deginv[c]
__global__ __launch_bounds__(256) void k_scan3(const int* __restrict__ cnt, int M,
                                               const int* __restrict__ bsum, int NBS,
                                               int* __restrict__ startArr, int* __restrict__ pos,
                                               float* __restrict__ deginv){
    int t = threadIdx.x;
    int base = blockIdx.x * SCB + t * 16;
    int vals[16];
    int s = 0;
    #pragma unroll
    for (int k = 0; k < 16; ++k){
        int i = base + k;
        vals[k] = (i < M) ? cnt[i] : 0;
        s += vals[k];
    }

    {
        int d0 = 0, d1 = 0;
        #pragma unroll
        for (int k = 0; k < 8; ++k){ d0 += vals[k]; d1 += vals[8 + k]; }
        int c0i = base >> 3;
        if (base < M)     deginv[c0i]     = d0 > 0 ? rsqrtf((float)d0) : 0.f;
        if (base + 8 < M) deginv[c0i + 1] = d1 > 0 ? rsqrtf((float)d1) : 0.f;
    }

    int lane = t & 63, w = t >> 6;

    int bp = 0, tp = 0;
    for (int i = lane; i < NBS; i += 64){
        int bv = bsum[i];
        if (i < (int)blockIdx.x) bp += bv;
        tp += bv;
    }
    #pragma unroll
    for (int o = 1; o < 64; o <<= 1){ bp += __shfl_xor(bp, o); tp += __shfl_xor(tp, o); }

    int v = s;
    #pragma unroll
    for (int o = 1; o < 64; o <<= 1){
        int u = __shfl_up(v, o);
        if (lane >= o) v += u;
    }
    __shared__ int wsum[4];
    if (lane == 63) wsum[w] = v;
    __syncthreads();
    int excl = v - s + bp;
    for (int i = 0; i < w; ++i) excl += wsum[i];
    #pragma unroll
    for (int k = 0; k < 16; ++k){
        int i = base + k;
        if (i < M){ startArr[i] = excl; pos[i] = excl; excl += vals[k]; }
    }
    if (blockIdx.x == (unsigned)(gridDim.x - 1) && t == 0) startArr[M] = tp;
}

// ---- place edges sorted by (col,type); coef inline ----
// meta x = cl<<20 | type<<17 | row   (row < 2^17; cl = c % CPB, 5 bits; run key = top 12..>>17)
__global__ __launch_bounds__(256) void k_place(const int* __restrict__ row, const int* __restrict__ col,
                                               const int* __restrict__ et, const float* __restrict__ ew,
                                               const float* __restrict__ deginv,
                                               int E, int* __restrict__ pos8, int2* __restrict__ pkm){
    int e = blockIdx.x * 256 + threadIdx.x;
    if (e >= E) return;
    int r = row[e], c = col[e], t = et[e];
    float cf = deginv[r] * deginv[c] * ew[e];
    int p = atomicAdd(&pos8[(c << 3) + t], 1);
    int cl = c - (c / CPB) * CPB;
    union { float f; int i; } cv; cv.f = cf;
    pkm[p] = make_int2((cl << 20) | (t << 17) | r, cv.i);
}

// ---- fused aggregate + transform conv ----
// out[c] = bias + sum_t ( sum_{e: col=c, type=t} coef_e * x[row_e] ) @ W[t]
// 512 threads = 8 waves; block owns 20 cols; 40 KB LDS -> 4 blocks/CU = 32 waves/CU
// (160 KB LDS exactly). vs CPB=16: B-stream 1.64 -> 1.31 GB (-20%) at IDENTICAL
// occupancy — phase 2 is an m-loop (rows 0-15, 16-19) reusing each B register twice.
// Phase 1 (scalar control plane, r6-proven): wave owns 2-3 cols (balanced split of 20
//   over 8 waves); metas s_load'd; 16-deep masked gather batches.
// Phase 2: wave nt=wid, M=20 (m-loop 2, second tile row-clamped), K=1024.
// Epilogue via 20x128 fp32 LDS tile -> coalesced stores (two passes for rows 16-19).
template<int MODE>
__global__ __launch_bounds__(512, 8) void k_fused(const unsigned short* __restrict__ xbin,
                                                  const unsigned short* __restrict__ wpk,
                                                  const int* __restrict__ cs8,
                                                  const int2* __restrict__ pkm,
                                                  const float* __restrict__ bias,
                                                  unsigned short* __restrict__ zb,
                                                  const unsigned short* __restrict__ xb2,
                                                  const unsigned short* __restrict__ z1b2,
                                                  float* __restrict__ outS,
                                                  float* __restrict__ outH,
                                                  int N, int wslot){
    __shared__ unsigned short s[CPB * 1024];    // 40 KB: bf16 A-tile, then fp32 out-tile
    int tid = threadIdx.x;
    int wid = tid >> 6, lane = tid & 63;
    int c0 = blockIdx.x * CPB;

    // zero the A-tile (2560 uint4 / 512 threads)
    uint4 z4 = {0u, 0u, 0u, 0u};
    #pragma unroll
    for (int k = 0; k < 5; ++k) ((uint4*)s)[tid + 512 * k] = z4;
    __syncthreads();

#define FLUSH() *(uint32_t*)((char*)s + flushByte) = packrn(a0, a1)
#define PROC(mx, cf, u) do{                                                       \
        int fk_ = (int)(((unsigned)(mx)) >> 17);                                  \
        if (fk_ != fkPrev){                                                       \
            if (fkPrev >= 0) FLUSH();                                             \
            fkPrev = fk_;                                                         \
            flushByte = (fk_ << 8) + ((lane << 2) ^ ((fk_ << 1) & 0x70));         \
            a0 = 0.f; a1 = 0.f;                                                   \
        }                                                                         \
        a0 = fmaf(cf, bf2f((u) & 0xFFFFu), a0);                                   \
        a1 = fmaf(cf, bf2f((u) >> 16),     a1); }while(0)
#define XROW(mx) ((const uint32_t*)xbin)[((size_t)(((mx) & 0x1FFFF) << 6)) + lane]

    // ---- phase 1: 2-3 cols per wave, one contiguous edge range, scalar metas ----
    {
        int cLo = c0 + ((wid * CPB) >> 3);
        int cHi = c0 + (((wid + 1) * CPB) >> 3);
        if (cLo > N) cLo = N;
        if (cHi > N) cHi = N;
        if (cLo < cHi){
            int e  = __builtin_amdgcn_readfirstlane(cs8[cLo * NREL]);
            int eE = __builtin_amdgcn_readfirstlane(cs8[cHi * NREL]);
            int fkPrev = -1, flushByte = 0;
            float a0 = 0.f, a1 = 0.f;
            const int* __restrict__ mp = (const int*)pkm;   // uniform -> s_load path
            while (e < eE){
                int n = eE - e; if (n > 16) n = 16;
                int mxs[16]; float cfs[16]; uint32_t u[16];
                int mprev = 0;
                #pragma unroll
                for (int k = 0; k < 16; ++k){
                    int live = k < n;                    // wave-uniform
                    int raw  = mp[2 * (e + k)];          // consecutive scalar loads (pkm padded +16)
                    float rc = asf(mp[2 * (e + k) + 1]);
                    int mx = (k == 0) ? raw : (live ? raw : mprev);
                    mxs[k] = mx; mprev = mx;
                    cfs[k] = live ? rc : 0.f;            // dead slot: same run key, zero coef
                }
                #pragma unroll
                for (int k = 0; k < 16; ++k) u[k] = XROW(mxs[k]);
                __builtin_amdgcn_sched_barrier(0);
                #pragma unroll
                for (int k = 0; k < 16; ++k) PROC(mxs[k], cfs[k], u[k]);
                e += n;
            }
            if (fkPrev >= 0) FLUSH();
        }
    }
#undef PROC
#undef FLUSH
#undef XROW
    __syncthreads();

    // ---- phase 2: wave nt=wid: M=20 via m-loop (B regs reused), K=1024 ----
    int nt = wid;
    f32x4 acc0 = (f32x4){0,0,0,0}, acc1 = (f32x4){0,0,0,0};

    int al = lane & 15, ak2 = (lane >> 4) * 16;
    int swz = (al & 7) << 4;
    const char* rowA0 = (const char*)s + al * 2048;
    int r1c = 16 + al; if (r1c > CPB - 1) r1c = CPB - 1;     // clamp: rows 16-19 valid, rest discarded
    const char* rowA1 = (const char*)s + r1c * 2048;         // (16+al)&7 == al&7, swizzle consistent

    const short8* bbase = (const short8*)wpk + (size_t)wslot * 2048 + lane;

    __builtin_amdgcn_s_setprio(1);
    #pragma unroll 4
    for (int ksg = 0; ksg < 32; ++ksg){
        int off = (ksg * 64 + ak2) ^ swz;
        short8 A0 = *(const short8*)(rowA0 + off);
        short8 A1 = *(const short8*)(rowA1 + off);
        int t = ksg >> 2, ksl = ksg & 3;
        short8 B = (bbase + (size_t)t * 2048)[(nt * 4 + ksl) * 64];
        acc0 = __builtin_amdgcn_mfma_f32_16x16x32_bf16(A0, B, acc0, 0, 0, 0);
        acc1 = __builtin_amdgcn_mfma_f32_16x16x32_bf16(A1, B, acc1, 0, 0, 0);
    }
    __builtin_amdgcn_s_setprio(0);
    __syncthreads();   // all A-reads done; reuse s as fp32 out-tile

    // ---- stage C tile to LDS (bias + relu applied here) ----
    float* ot = (float*)s;   // [CPB][128]
    int crb = (lane >> 4) * 4, dcl = lane & 15;
    {
        int d = nt * 16 + dcl;
        float bv = bias[d];
        #pragma unroll
        for (int r = 0; r < 4; ++r){
            int row0 = crb + r;
            float v0 = acc0[r] + bv;
            if (MODE == 0) v0 = fmaxf(v0, 0.f);
            ot[row0 * DIM + d] = v0;
            int row1 = 16 + crb + r;
            if (row1 < CPB){
                float v1 = acc1[r] + bv;
                if (MODE == 0) v1 = fmaxf(v1, 0.f);
                ot[row1 * DIM + d] = v1;
            }
        }
    }
    __syncthreads();

    // ---- coalesced output ----
    if (MODE == 0){
        if (tid < CPB * 16){
            int rowi = tid >> 4, seg = tid & 15;
            int c = c0 + rowi;
            if (c < N){
                const float* src = ot + rowi * DIM + seg * 8;
                uint4 vv;
                vv.x = packrn(src[0], src[1]);
                vv.y = packrn(src[2], src[3]);
                vv.z = packrn(src[4], src[5]);
                vv.w = packrn(src[6], src[7]);
                *(uint4*)(zb + ((size_t)c << 7) + seg * 8) = vv;
            }
        }
    } else {
        #pragma unroll
        for (int pass = 0; pass < 2; ++pass){
            int rowi = (pass == 0) ? (tid >> 5) : (16 + (tid >> 5));
            bool act = (pass == 0) || (tid < (CPB - 16) * 32);
            int c = c0 + rowi;
            if (act && c < N){
                int q = tid & 31;
                int d0 = q * 4;
                size_t o = ((size_t)c << 7) + d0;
                ushort4 xv4 = *(const ushort4*)(xb2 + o);
                ushort4 zv4 = *(const ushort4*)(z1b2 + o);
                const float* src = ot + rowi * DIM + d0;
                f32x4 S, H;
                {
                    float xv = bf2f(xv4.x), z1 = bf2f(zv4.x), v = src[0];
                    S.x = (xv + z1 + v) * 0.25f; H.x = (z1 + v) * (1.0f / 3.0f);
                }
                {
                    float xv = bf2f(xv4.y), z1 = bf2f(zv4.y), v = src[1];
                    S.y = (xv + z1 + v) * 0.25f; H.y = (z1 + v) * (1.0f / 3.0f);
                }
                {
                    float xv = bf2f(xv4.z), z1 = bf2f(zv4.z), v = src[2];
                    S.z = (xv + z1 + v) * 0.25f; H.z = (z1 + v) * (1.0f / 3.0f);
                }
                {
                    float xv = bf2f(xv4.w), z1 = bf2f(zv4.w), v = src[3];
                    S.w = (xv + z1 + v) * 0.25f; H.w = (z1 + v) * (1.0f / 3.0f);
                }
                __builtin_nontemporal_store(S, (f32x4*)(outS + o));
                __builtin_nontemporal_store(H, (f32x4*)(outH + o));
            }
        }
    }
}

extern "C" void kernel_launch(void* const* d_in, const int* in_sizes, int n_in,
                              void* d_out, int out_size, void* d_ws, size_t ws_size,
                              hipStream_t stream) {
    const float* x  = (const float*)d_in[0];
    const int*   ei = (const int*)d_in[1];
    const int*   et = (const int*)d_in[2];
    const float* ew = (const float*)d_in[3];
    const float* W1 = (const float*)d_in[4];
    const float* b1 = (const float*)d_in[5];
    const float* W2 = (const float*)d_in[6];
    const float* b2 = (const float*)d_in[7];

    int E = in_sizes[2];
    int N = in_sizes[0] / DIM;
    const int* row = ei;
    const int* col = ei + E;

    float* out = (float*)d_out;
    int ND  = N * DIM;
    int ND4 = ND / 4;
    float* zS = out;        // slot 0: z_star
    float* zH = out + ND;   // slot 1: z_sharp

    int M8   = N * NREL;
    int NBS8 = cdiv(M8, SCB);

    // ---- workspace carve (~70 MB) ----
    char* wsb = (char*)d_ws;
    size_t off = 0;
    auto take = [&](size_t bytes) -> char* {
        char* p = wsb + off;
        off = (off + bytes + 255) & ~(size_t)255;
        return p;
    };
    int*            cnt8     = (int*)           take((size_t)M8 * 4);
    int*            start8   = (int*)           take(((size_t)M8 + 1) * 4);
    int*            pos8     = (int*)           take((size_t)M8 * 4);
    int*            bsum     = (int*)           take(((size_t)NBS8 + 1) * 4);
    float*          deginv   = (float*)         take((size_t)N * 4);
    int2*           pkm      = (int2*)          take(((size_t)E + 16) * 8);       // +16: batch overread pad
    unsigned short* wpk      = (unsigned short*)take((size_t)16 * 2048 * 8 * 2);  // 512 KB
    unsigned short* xb       = (unsigned short*)take((size_t)ND * 2);
    unsigned short* z1b      = (unsigned short*)take((size_t)ND * 2);
    (void)n_in; (void)out_size; (void)ws_size;

    (void)hipMemsetAsync(cnt8, 0, (size_t)M8 * 4, stream);

    int eb  = cdiv(E, 256);
    int nb4 = cdiv(ND4, 256);
    k_prep  <<<nb4 + eb + 128, 256, 0, stream>>>(x, xb, ND4, col, et, E, cnt8, nb4, eb, W1, W2, wpk);
    k_scan1 <<<NBS8, 256, 0, stream>>>(cnt8, M8, bsum);
    k_scan3 <<<NBS8, 256, 0, stream>>>(cnt8, M8, bsum, NBS8, start8, pos8, deginv);
    k_place <<<eb, 256, 0, stream>>>(row, col, et, ew, deginv, E, pos8, pkm);

    int fb = cdiv(N, CPB);
    // conv1: z1b = bf16(relu(agg(x) @ W1 + b1))
    k_fused<0><<<fb, 512, 0, stream>>>(xb, wpk, start8, pkm, b1, z1b, nullptr, nullptr, nullptr, nullptr, N, 0);
    // conv2: fused z_star/z_sharp from xb, z1b, agg(z1b) @ W2 + b2
    k_fused<1><<<fb, 512, 0, stream>>>(z1b, wpk, start8, pkm, b2, nullptr, xb, z1b, zS, zH, N, 8);
}